// Round 8
// baseline (143.566 us; speedup 1.0000x reference)
//
#include <hip/hip_runtime.h>
#include <hip/hip_bf16.h>
#include <math.h>

typedef __bf16 bf16;
typedef __attribute__((ext_vector_type(8))) __bf16 bf16x8;
typedef __attribute__((ext_vector_type(4))) __bf16 bf16x4;
typedef __attribute__((ext_vector_type(2))) __bf16 bf16x2;
typedef __attribute__((ext_vector_type(4))) float f32x4;
typedef __attribute__((ext_vector_type(16))) float f32x16;
typedef __attribute__((ext_vector_type(4))) unsigned u32x4;

#define MFMA(a,b,c)   __builtin_amdgcn_mfma_f32_16x16x32_bf16(a,b,c,0,0,0)
#define MFMA32(a,b,c) __builtin_amdgcn_mfma_f32_32x32x16_bf16(a,b,c,0,0,0)

static constexpr int Bb = 4, Nn = 2048, Hh = 4;
// SS2 = SCALE^0.5 * sqrt(log2(e)) so that S' = S * log2(e); exp2(S') = e^S
static constexpr float SS2 = 0.4246609001440095f;

__device__ __forceinline__ void lds16(const bf16* src, bf16* dst) {
  __builtin_amdgcn_global_load_lds(
      (const __attribute__((address_space(1))) void*)src,
      (__attribute__((address_space(3))) void*)dst, 16, 0, 0);
}

__device__ __forceinline__ f32x16 zero16() {
  f32x16 t;
#pragma unroll
  for (int i = 0; i < 16; ++i) t[i] = 0.f;
  return t;
}

// ---------------- prep: weight transposes/casts + fold scaffolding + x->bf16 ----------------
__global__ __launch_bounds__(256) void prep_k(
    const float* Wqk, const float* Wv, const float* Wout, const float* bout,
    const float* Wf1, const float* Wf2, const float* x0, const float* x1,
    bf16* wqkv_t, bf16* wout_b, bf16* wfold_t, bf16* wf1b_t, bf16* wf2_t,
    bf16* xb0, bf16* xb1) {
  int id = blockIdx.x * 256 + threadIdx.x;
  if (id < 65536) { int k = id >> 8, n = id & 255; wqkv_t[n*256 + k] = (bf16)Wqk[id]; return; }
  id -= 65536;
  if (id < 65536) { int k = id >> 8, n = id & 255; wqkv_t[(256 + n)*256 + k] = (bf16)Wv[id]; return; }
  id -= 65536;
  if (id < 98304) {
    if (id < 65536) { wout_b[id] = (bf16)Wout[id]; }
    else { int id3 = id - 65536; int r = id3 >> 8, k = id3 & 255;
           wout_b[(256 + r)*256 + k] = (r == 0) ? (bf16)bout[k] : (bf16)0.f; }
    return; }
  id -= 98304;
  if (id < 131072) { int o = id & 511, k = id >> 9; wfold_t[o*512 + k] = (bf16)Wf1[k*512 + o]; return; }
  id -= 131072;
  if (id < 131072) { int o = id & 511, k = id >> 9; wf1b_t[o*256 + k] = (bf16)Wf1[(256 + k)*512 + o]; return; }
  id -= 131072;
  if (id < 131072) { int k = id >> 8, n = id & 255; wf2_t[n*512 + k] = (bf16)Wf2[id]; return; }
  id -= 131072;
  if (id < 1048576) {
    const float* xs = (id < 524288) ? x0 : x1;
    bf16* xd = (id < 524288) ? xb0 : xb1;
    int j = (id < 524288) ? id : id - 524288;
    f32x4 v = *reinterpret_cast<const f32x4*>(&xs[(size_t)j * 4]);
    bf16x4 o; o[0] = (bf16)v[0]; o[1] = (bf16)v[1]; o[2] = (bf16)v[2]; o[3] = (bf16)v[3];
    *reinterpret_cast<bf16x4*>(&xd[(size_t)j * 4]) = o;
  }
}

// ---------------- pipelined MFMA GEMM, 128xBN tile, BK=64, dbuf + lds16 ----------------
// (unchanged from round 7)
template<int MODE, int BN, int MINW, int REMAP>
__global__ __launch_bounds__(256, MINW) void gemm_k(
    const bf16* Aa0, const bf16* Aa1, const bf16* Ac0, const bf16* Ac1,
    const bf16* Wt, const float* bias,
    bf16* ob0, bf16* ob1, float* of0, float* of1,
    const float* res0, const float* res1) {
  constexpr int KD  = (MODE == 3 || MODE == 4) ? 512 : 256;
  constexpr int LDA = (MODE == 4) ? 512 : 256;
  constexpr int NKC = KD / 64;
  constexpr int NF  = BN / 32;

  int bx = blockIdx.x, by = blockIdx.y, bz = blockIdx.z;
  if constexpr (REMAP) {
    int id = blockIdx.x + 64 * (blockIdx.y + 4 * blockIdx.z);
    bx = ((id & 7) << 3) + ((id >> 3) & 7);
    by = (id >> 6) & 3;
    bz = id >> 8;
  }

  const bf16* Aa = bz ? Aa1 : Aa0;
  const bf16* Ac = bz ? Ac1 : Ac0;
  bf16*  ob = bz ? ob1 : ob0;
  float* of = bz ? of1 : of0;
  const float* res = bz ? res1 : res0;

  const int tid = threadIdx.x;
  const int lane = tid & 63;
  const int w = tid >> 6;
  const int wr = w >> 1, wc = w & 1;
  const int m0r = bx * 128;
  const int n0 = by * BN;
  const int r15 = lane & 15, g = lane >> 4, rb = r15 & 7;
  const int l3 = lane >> 3, l7 = lane & 7;
  const int swzc = (l7 ^ l3) * 8;

  __shared__ bf16 At[2][8192];
  __shared__ bf16 Bt[2][BN * 64];

  const bf16* aA = Aa + (size_t)(m0r + w*32 + l3) * LDA + swzc;
  const bf16* aC = (MODE == 3) ? (Ac + (size_t)(m0r + w*32 + l3) * 256 + swzc) : nullptr;
  const bf16* bB = Wt + (size_t)(n0 + w*(BN/4) + l3) * KD + swzc;
  const int adst = (w*32) * 64;
  const int bdst = (w*(BN/4)) * 64;

  auto stage = [&](int buf, int kc) {
    const bf16* ab; int kcol;
    if constexpr (MODE == 3) {
      if (kc < 4) { ab = aA; kcol = kc * 64; } else { ab = aC; kcol = (kc - 4) * 64; }
    } else { ab = aA; kcol = kc * 64; }
#pragma unroll
    for (int i = 0; i < 4; i++)
      lds16(ab + kcol + (size_t)i * 8 * LDA, &At[buf][adst + i*512]);
#pragma unroll
    for (int i = 0; i < NF; i++)
      lds16(bB + kc*64 + (size_t)i * 8 * KD, &Bt[buf][bdst + i*512]);
  };

  f32x4 acc[4][NF];
#pragma unroll
  for (int i = 0; i < 4; i++)
#pragma unroll
    for (int j = 0; j < NF; j++) acc[i][j] = f32x4{0.f, 0.f, 0.f, 0.f};

  const int rx0 = ((0*4 + g) ^ rb) << 4;
  const int rx1 = ((1*4 + g) ^ rb) << 4;

  auto compute = [&](int cur) {
    const char* Ap = (const char*)&At[cur][0];
    const char* Bp = (const char*)&Bt[cur][0];
    __builtin_amdgcn_s_setprio(1);
#pragma unroll
    for (int ks = 0; ks < 2; ++ks) {
      const int rx = ks ? rx1 : rx0;
      bf16x8 af[4], bfr[NF];
#pragma unroll
      for (int mf = 0; mf < 4; ++mf)
        af[mf] = *reinterpret_cast<const bf16x8*>(Ap + (wr*64 + mf*16 + r15) * 128 + rx);
#pragma unroll
      for (int nf = 0; nf < NF; ++nf)
        bfr[nf] = *reinterpret_cast<const bf16x8*>(Bp + (wc*(BN/2) + nf*16 + r15) * 128 + rx);
#pragma unroll
      for (int mf = 0; mf < 4; ++mf)
#pragma unroll
        for (int nf = 0; nf < NF; ++nf)
          acc[mf][nf] = MFMA(af[mf], bfr[nf], acc[mf][nf]);
    }
    __builtin_amdgcn_s_setprio(0);
  };

  stage(0, 0);
  int cur = 0;
  for (int kc = 0; kc < NKC - 1; ++kc) {
    stage(cur ^ 1, kc + 1);
    if constexpr (NF == 4) asm volatile("s_waitcnt vmcnt(8)" ::: "memory");
    else                   asm volatile("s_waitcnt vmcnt(6)" ::: "memory");
    __builtin_amdgcn_sched_barrier(0);
    __builtin_amdgcn_s_barrier();
    __builtin_amdgcn_sched_barrier(0);
    compute(cur);
    asm volatile("s_waitcnt lgkmcnt(0)" ::: "memory");
    __builtin_amdgcn_sched_barrier(0);
    __builtin_amdgcn_s_barrier();
    __builtin_amdgcn_sched_barrier(0);
    cur ^= 1;
  }
  asm volatile("s_waitcnt vmcnt(0)" ::: "memory");
  __builtin_amdgcn_sched_barrier(0);
  __builtin_amdgcn_s_barrier();
  __builtin_amdgcn_sched_barrier(0);
  compute(cur);

  // ---- epilogue ----
#pragma unroll
  for (int mf = 0; mf < 4; ++mf)
#pragma unroll
    for (int nf = 0; nf < NF; ++nf) {
      f32x4 c = acc[mf][nf];
      int cg = n0 + wc*(BN/2) + nf*16 + r15;
#pragma unroll
      for (int r = 0; r < 4; ++r) {
        int rg = m0r + wr*64 + mf*16 + g*4 + r;
        if constexpr (MODE == 5) {
          int b = rg >> 11, n = rg & 2047;
          if (cg < 256) {
            float val = (c[r] + bias[cg]) * SS2;
            int h = cg >> 6, dh = cg & 63;
            ob[(((size_t)(b*Hh + h)) * Nn + n) * 64 + dh] = (bf16)val;
          } else {
            int c2 = cg - 256;
            float val = c[r] + res[c2];            // res carries bv
            int h = c2 >> 6, dh = c2 & 63;
            ((bf16*)of)[(((size_t)(b*Hh + h)) * 64 + dh) * Nn + n] = (bf16)val;
          }
        } else if constexpr (MODE == 6) {
          if (rg < 256) ob[(size_t)cg * 512 + 256 + rg] = (bf16)c[r];
          else if (rg == 256) of[cg] = c[r] + bias[cg];   // bias = bf1
        } else if constexpr (MODE == 3) {
          ob[(size_t)rg * 512 + cg] = (bf16)(c[r] + bias[cg]);
        } else {   // MODE 4
          of[(size_t)rg * 256 + cg] = c[r] + bias[cg] + (float)Ac[(size_t)rg * 256 + cg];
        }
      }
    }
}

// ---------------- fused dual-direction attention: 64 q-rows/WAVE ----------------
// Block = 4 waves x 64 i = 256 i-rows; grid 256 blocks = 1 block/CU.
// K/V LDS reads per wave unchanged (16 KB/tile) but amortized over 2x MFMA ->
// MFMA-bound instead of LDS-read-bound. Double-buffered K/V via global_load_lds
// + counted vmcnt + raw barriers, XOR-swizzled LDS. S^T = mfma32(K,Q); P in
// registers via exp2 + cvt_pk + permlane32_swap; rowsum = per-lane f32 VALU
// (lane = i in S^T layout) + epilogue LDS redistribute.
__global__ __launch_bounds__(256, 1) void attn_k(
    const bf16* qks0, const bf16* qks1, const bf16* vT0, const bf16* vT1,
    bf16* m0o, bf16* m1o) {
  const int B = blockIdx.x + 8 * (blockIdx.y + 16 * blockIdx.z);
  const int xcd = B & 7, kk = B >> 3;          // kk 0..31
  const int group = 4 * xcd + (kk >> 3);       // 0..31 = dir*16 + bh
  const int it = kk & 7;
  const int bh = group & 15, dir = group >> 4;

  const bf16* Q  = (dir ? qks1 : qks0) + (size_t)bh * (Nn * 64);
  const bf16* Kp = (dir ? qks0 : qks1) + (size_t)bh * (Nn * 64);
  const bf16* Vp = (dir ? vT0  : vT1 ) + (size_t)bh * (64 * Nn);
  bf16* out = dir ? m1o : m0o;
  const int b = bh >> 2, h = bh & 3;

  const int tid = threadIdx.x, lane = tid & 63, w = tid >> 6;
  const int l31 = lane & 31, hi = lane >> 5, xr = l31 & 7;
  const int iw = it * 256 + w * 64;            // wave's first q-row

  __shared__ bf16 Kt[2][4096];                 // [buf][64 j x 64 d], swizzled
  __shared__ bf16 Vt[2][4096];                 // [buf][64 d x 64 j], swizzled
  __shared__ float Rt[4][64];                  // per-wave rowsum redistribute

  // ---- Q fragments (B-operand: col i = l31 (+32*ih), k d = kt*16 + hi*8 + e) ----
  bf16x8 qf[2][4];
#pragma unroll
  for (int ih = 0; ih < 2; ++ih)
#pragma unroll
    for (int kt = 0; kt < 4; ++kt)
      qf[ih][kt] = *reinterpret_cast<const bf16x8*>(
          &Q[(size_t)(iw + ih*32 + l31) * 64 + kt*16 + hi*8]);

  f32x16 acc[2][2];
#pragma unroll
  for (int ih = 0; ih < 2; ++ih)
#pragma unroll
    for (int nt = 0; nt < 2; ++nt) acc[ih][nt] = zero16();
  float rsum0 = 0.f, rsum1 = 0.f;   // per-lane: sum_j E for i = ih*32 + l31 (this hi's j-subset)

  // ---- staging (pre-swizzled global sources, linear LDS dests) ----
  const int l3 = lane >> 3, l7 = lane & 7;
  const int swz = ((l7 ^ l3) * 8);
  const bf16* ks0 = Kp + (size_t)(w*16 +     l3) * 64 + swz;
  const bf16* ks1 = Kp + (size_t)(w*16 + 8 + l3) * 64 + swz;
  const bf16* vs0 = Vp + (size_t)(w*16 +     l3) * 2048 + swz;
  const bf16* vs1 = Vp + (size_t)(w*16 + 8 + l3) * 2048 + swz;
  const int kd0 = (w*16    ) * 64;
  const int kd1 = (w*16 + 8) * 64;

  auto stage = [&](int buf, int j0) {
    lds16(ks0 + (size_t)j0 * 64, &Kt[buf][kd0]);
    lds16(ks1 + (size_t)j0 * 64, &Kt[buf][kd1]);
    lds16(vs0 + j0,              &Vt[buf][kd0]);
    lds16(vs1 + j0,              &Vt[buf][kd1]);
  };

  // read-offset tables (bytes)
  int kby[2][4], vby[2][4];
#pragma unroll
  for (int jm = 0; jm < 2; ++jm)
#pragma unroll
    for (int kt = 0; kt < 4; ++kt)
      kby[jm][kt] = (jm*32 + l31) * 128 + (((2*kt + hi) ^ xr) << 4);
#pragma unroll
  for (int nt = 0; nt < 2; ++nt)
#pragma unroll
    for (int gg = 0; gg < 4; ++gg)
      vby[nt][gg] = (nt*32 + l31) * 128 + (((2*gg + hi) ^ xr) << 4);

  auto compute_tile = [&](int cur) {
    const char* Kb = (const char*)&Kt[cur][0];
    const char* Vb = (const char*)&Vt[cur][0];
    bf16x8 pa[2][4];   // [ih][gg] PV A-fragments
#pragma unroll
    for (int jm = 0; jm < 2; ++jm) {
      // --- QK^T for this jm (j-half): S^T[j][i], 4 K-frag reads, 8 mfma ---
      f32x16 st0 = zero16(), st1 = zero16();
      __builtin_amdgcn_s_setprio(1);
#pragma unroll
      for (int kt = 0; kt < 4; ++kt) {
        bf16x8 kf = *reinterpret_cast<const bf16x8*>(Kb + kby[jm][kt]);
        st0 = MFMA32(kf, qf[0][kt], st0);
        st1 = MFMA32(kf, qf[1][kt], st1);
      }
      __builtin_amdgcn_s_setprio(0);
      // --- exp2 + VALU rowsum + cvt_pk + permlane32_swap -> pa (in-register) ---
#pragma unroll
      for (int ih = 0; ih < 2; ++ih) {
        const f32x16& st = ih ? st1 : st0;
        unsigned dw[8];
#pragma unroll
        for (int s = 0; s < 8; ++s) {
          float e0 = __builtin_amdgcn_exp2f(st[2*s]);
          float e1 = __builtin_amdgcn_exp2f(st[2*s + 1]);
          if (ih) rsum1 += e0 + e1; else rsum0 += e0 + e1;
          asm("v_cvt_pk_bf16_f32 %0, %1, %2" : "=v"(dw[s]) : "v"(e0), "v"(e1));
        }
#pragma unroll
        for (int kt2 = 0; kt2 < 2; ++kt2) {
          unsigned a0 = dw[4*kt2 + 0], b0 = dw[4*kt2 + 2];
          unsigned a1 = dw[4*kt2 + 1], b1 = dw[4*kt2 + 3];
          // a' = [a.lo | b.lo], b' = [a.hi | b.hi]
          asm volatile("v_permlane32_swap_b32 %0, %1" : "+v"(a0), "+v"(b0));
          asm volatile("v_permlane32_swap_b32 %0, %1" : "+v"(a1), "+v"(b1));
          u32x4 uu; uu[0] = a0; uu[1] = a1; uu[2] = b0; uu[3] = b1;
          pa[ih][jm*2 + kt2] = __builtin_bit_cast(bf16x8, uu);
        }
      }
    }
    // --- PV: 8 V-frag reads, 16 mfma, 4 independent acc chains ---
    __builtin_amdgcn_s_setprio(1);
#pragma unroll
    for (int gg = 0; gg < 4; ++gg) {
      bf16x8 v0 = *reinterpret_cast<const bf16x8*>(Vb + vby[0][gg]);
      bf16x8 v1 = *reinterpret_cast<const bf16x8*>(Vb + vby[1][gg]);
      acc[0][0] = MFMA32(pa[0][gg], v0, acc[0][0]);
      acc[1][0] = MFMA32(pa[1][gg], v0, acc[1][0]);
      acc[0][1] = MFMA32(pa[0][gg], v1, acc[0][1]);
      acc[1][1] = MFMA32(pa[1][gg], v1, acc[1][1]);
    }
    __builtin_amdgcn_s_setprio(0);
  };

  // ---- pipelined main loop: 32 j-tiles, last one peeled ----
  stage(0, 0);
  int cur = 0;
  for (int jt = 0; jt < 31; ++jt) {
    stage(cur ^ 1, (jt + 1) << 6);
    asm volatile("s_waitcnt vmcnt(4)" ::: "memory");
    __builtin_amdgcn_sched_barrier(0);
    __builtin_amdgcn_s_barrier();
    __builtin_amdgcn_sched_barrier(0);
    compute_tile(cur);
    asm volatile("s_waitcnt lgkmcnt(0)" ::: "memory");
    __builtin_amdgcn_sched_barrier(0);
    __builtin_amdgcn_s_barrier();
    __builtin_amdgcn_sched_barrier(0);
    cur ^= 1;
  }
  asm volatile("s_waitcnt vmcnt(0)" ::: "memory");
  __builtin_amdgcn_sched_barrier(0);
  __builtin_amdgcn_s_barrier();
  __builtin_amdgcn_sched_barrier(0);
  compute_tile(cur);

  // ---- epilogue: finish rowsum (lane=i), redistribute to reg-rows via LDS ----
  rsum0 += __shfl_xor(rsum0, 32);
  rsum1 += __shfl_xor(rsum1, 32);
  if (hi == 0) {
    Rt[w][l31]      = rsum0;
    Rt[w][32 + l31] = rsum1;
  }
  // wave-internal RAW on LDS: compiler inserts lgkmcnt wait
  f32x4 rv[2][4];
#pragma unroll
  for (int ih = 0; ih < 2; ++ih)
#pragma unroll
    for (int q = 0; q < 4; ++q)
      rv[ih][q] = *reinterpret_cast<const f32x4*>(&Rt[w][ih*32 + 8*q + 4*hi]);
#pragma unroll
  for (int ih = 0; ih < 2; ++ih)
#pragma unroll
    for (int r = 0; r < 16; ++r) {
      float inv = 1.0f / rv[ih][r >> 2][r & 3];
      int row = iw + ih*32 + (r & 3) + 8*(r >> 2) + 4*hi;
#pragma unroll
      for (int nt = 0; nt < 2; ++nt) {
        int col = h*64 + nt*32 + l31;
        out[((size_t)b * Nn + row) * 256 + col] = (bf16)(acc[ih][nt][r] * inv);
      }
    }
}

// ---------------- LayerNorm + exact GELU: one wave per 512-col row ----------------
__global__ __launch_bounds__(256) void ln_gelu_k(
    bf16* hg, const float* g, const float* bb) {
  const int row = (blockIdx.x << 2) + (threadIdx.x >> 6);
  const int lane = threadIdx.x & 63;
  bf16* hr = hg + (size_t)row * 512 + lane * 8;
  bf16x8 v = *reinterpret_cast<const bf16x8*>(hr);
  float f[8];
  float s = 0.f, sq = 0.f;
#pragma unroll
  for (int i = 0; i < 8; ++i) { f[i] = (float)v[i]; s += f[i]; sq += f[i]*f[i]; }
#pragma unroll
  for (int m = 1; m < 64; m <<= 1) { s += __shfl_xor(s, m); sq += __shfl_xor(sq, m); }
  float mu = s * (1.f / 512.f);
  float var = sq * (1.f / 512.f) - mu * mu;
  float rsv = rsqrtf(var + 1e-5f);
  f32x4 g0 = *reinterpret_cast<const f32x4*>(&g[lane*8]);
  f32x4 g1 = *reinterpret_cast<const f32x4*>(&g[lane*8 + 4]);
  f32x4 b0 = *reinterpret_cast<const f32x4*>(&bb[lane*8]);
  f32x4 b1 = *reinterpret_cast<const f32x4*>(&bb[lane*8 + 4]);
  bf16x8 o;
#pragma unroll
  for (int i = 0; i < 8; ++i) {
    float gv = (i < 4) ? g0[i] : g1[i-4];
    float bv = (i < 4) ? b0[i] : b1[i-4];
    float xn = (f[i] - mu) * rsv * gv + bv;
    float ge = 0.5f * xn * (1.f + erff(xn * 0.70710678118f));
    o[i] = (bf16)ge;
  }
  *reinterpret_cast<bf16x8*>(hr) = o;
}

extern "C" void kernel_launch(void* const* d_in, const int* in_sizes, int n_in,
                              void* d_out, int out_size, void* d_ws, size_t ws_size,
                              hipStream_t stream) {
  (void)in_sizes; (void)n_in; (void)out_size; (void)ws_size;
  const float* x0   = (const float*)d_in[0];
  const float* x1   = (const float*)d_in[1];
  const float* Wqk  = (const float*)d_in[2];
  const float* bqk  = (const float*)d_in[3];
  const float* Wv   = (const float*)d_in[4];
  const float* bv   = (const float*)d_in[5];
  const float* Wout = (const float*)d_in[6];
  const float* bout = (const float*)d_in[7];
  const float* Wf1  = (const float*)d_in[8];
  const float* bf1  = (const float*)d_in[9];
  const float* ln_g = (const float*)d_in[10];
  const float* ln_b = (const float*)d_in[11];
  const float* Wf2  = (const float*)d_in[12];
  const float* bf2  = (const float*)d_in[13];
  float* y = (float*)d_out;

  bf16* p = (bf16*)d_ws;
  bf16* wqkv_t = p; p += 131072;
  bf16* wout_b = p; p += 98304;
  bf16* wfold_t = p; p += 262144;
  bf16* wf1b_t = p; p += 131072;
  bf16* wf2_t  = p; p += 131072;
  float* bfold = (float*)p; p += 1024;     // 512 f32
  bf16* xb0  = p; p += 2097152;
  bf16* xb1  = p; p += 2097152;
  bf16* qks0 = p; p += 2097152;
  bf16* qks1 = p; p += 2097152;
  bf16* vT0  = p; p += 2097152;
  bf16* vT1  = p; p += 2097152;
  bf16* m0   = p; p += 2097152;
  bf16* m1   = p; p += 2097152;
  bf16* hg0  = p; p += 4194304;
  bf16* hg1  = p; p += 4194304;

  dim3 blk(256);
  prep_k<<<6528, blk, 0, stream>>>(Wqk, Wv, Wout, bout, Wf1, Wf2, x0, x1,
                                   wqkv_t, wout_b, wfold_t, wf1b_t, wf2_t, xb0, xb1);
  // weight fold: Wc = [Wout; bout] @ Wf1b  -> wfold_t cols 256-511, bfold
  gemm_k<6,128,2,0><<<dim3(3, 4, 1), blk, 0, stream>>>(
      wout_b, wout_b, nullptr, nullptr, wf1b_t, bf1,
      wfold_t, wfold_t, bfold, bfold, nullptr, nullptr);
  gemm_k<5,128,2,1><<<dim3(64, 4, 2), blk, 0, stream>>>(
      xb0, xb1, nullptr, nullptr, wqkv_t, bqk,
      qks0, qks1, (float*)vT0, (float*)vT1, bv, bv);
  attn_k<<<dim3(8, 16, 2), blk, 0, stream>>>(qks0, qks1, vT0, vT1, m0, m1);
  gemm_k<3,128,2,1><<<dim3(64, 4, 2), blk, 0, stream>>>(
      xb0, xb1, m0, m1, wfold_t, bfold,
      hg0, hg1, nullptr, nullptr, nullptr, nullptr);
  ln_gelu_k<<<dim3(4096), blk, 0, stream>>>(hg0, ln_g, ln_b);
  gemm_k<4,64,3,1><<<dim3(64, 4, 2), blk, 0, stream>>>(
      hg0, hg1, xb0, xb1, wf2_t, bf2,
      nullptr, nullptr, y, y + 2097152, nullptr, nullptr);
}

// Round 9
// 129.354 us; speedup vs baseline: 1.1099x; 1.1099x over previous
//
#include <hip/hip_runtime.h>
#include <hip/hip_bf16.h>
#include <math.h>

typedef __bf16 bf16;
typedef __attribute__((ext_vector_type(8))) __bf16 bf16x8;
typedef __attribute__((ext_vector_type(4))) __bf16 bf16x4;
typedef __attribute__((ext_vector_type(2))) __bf16 bf16x2;
typedef __attribute__((ext_vector_type(4))) float f32x4;
typedef __attribute__((ext_vector_type(16))) float f32x16;
typedef __attribute__((ext_vector_type(4))) unsigned u32x4;

#define MFMA(a,b,c)   __builtin_amdgcn_mfma_f32_16x16x32_bf16(a,b,c,0,0,0)
#define MFMA32(a,b,c) __builtin_amdgcn_mfma_f32_32x32x16_bf16(a,b,c,0,0,0)

static constexpr int Bb = 4, Nn = 2048, Hh = 4;
// SS2 = SCALE^0.5 * sqrt(log2(e)) so that S' = S * log2(e); exp2(S') = e^S
static constexpr float SS2 = 0.4246609001440095f;

__device__ __forceinline__ void lds16(const bf16* src, bf16* dst) {
  __builtin_amdgcn_global_load_lds(
      (const __attribute__((address_space(1))) void*)src,
      (__attribute__((address_space(3))) void*)dst, 16, 0, 0);
}

__device__ __forceinline__ f32x16 zero16() {
  f32x16 t;
#pragma unroll
  for (int i = 0; i < 16; ++i) t[i] = 0.f;
  return t;
}

// ---------------- prep: weight transposes/casts + fold scaffolding + x->bf16 ----------------
__global__ __launch_bounds__(256) void prep_k(
    const float* Wqk, const float* Wv, const float* Wout, const float* bout,
    const float* Wf1, const float* Wf2, const float* x0, const float* x1,
    bf16* wqkv_t, bf16* wout_b, bf16* wfold_t, bf16* wf1b_t, bf16* wf2_t,
    bf16* xb0, bf16* xb1) {
  int id = blockIdx.x * 256 + threadIdx.x;
  if (id < 65536) { int k = id >> 8, n = id & 255; wqkv_t[n*256 + k] = (bf16)Wqk[id]; return; }
  id -= 65536;
  if (id < 65536) { int k = id >> 8, n = id & 255; wqkv_t[(256 + n)*256 + k] = (bf16)Wv[id]; return; }
  id -= 65536;
  if (id < 98304) {
    if (id < 65536) { wout_b[id] = (bf16)Wout[id]; }
    else { int id3 = id - 65536; int r = id3 >> 8, k = id3 & 255;
           wout_b[(256 + r)*256 + k] = (r == 0) ? (bf16)bout[k] : (bf16)0.f; }
    return; }
  id -= 98304;
  if (id < 131072) { int o = id & 511, k = id >> 9; wfold_t[o*512 + k] = (bf16)Wf1[k*512 + o]; return; }
  id -= 131072;
  if (id < 131072) { int o = id & 511, k = id >> 9; wf1b_t[o*256 + k] = (bf16)Wf1[(256 + k)*512 + o]; return; }
  id -= 131072;
  if (id < 131072) { int k = id >> 8, n = id & 255; wf2_t[n*512 + k] = (bf16)Wf2[id]; return; }
  id -= 131072;
  if (id < 1048576) {
    const float* xs = (id < 524288) ? x0 : x1;
    bf16* xd = (id < 524288) ? xb0 : xb1;
    int j = (id < 524288) ? id : id - 524288;
    f32x4 v = *reinterpret_cast<const f32x4*>(&xs[(size_t)j * 4]);
    bf16x4 o; o[0] = (bf16)v[0]; o[1] = (bf16)v[1]; o[2] = (bf16)v[2]; o[3] = (bf16)v[3];
    *reinterpret_cast<bf16x4*>(&xd[(size_t)j * 4]) = o;
  }
}

// ---------------- pipelined MFMA GEMM, 128xBN tile, BK=64, dbuf + lds16 ----------------
// (unchanged from round 7)
template<int MODE, int BN, int MINW, int REMAP>
__global__ __launch_bounds__(256, MINW) void gemm_k(
    const bf16* Aa0, const bf16* Aa1, const bf16* Ac0, const bf16* Ac1,
    const bf16* Wt, const float* bias,
    bf16* ob0, bf16* ob1, float* of0, float* of1,
    const float* res0, const float* res1) {
  constexpr int KD  = (MODE == 3 || MODE == 4) ? 512 : 256;
  constexpr int LDA = (MODE == 4) ? 512 : 256;
  constexpr int NKC = KD / 64;
  constexpr int NF  = BN / 32;

  int bx = blockIdx.x, by = blockIdx.y, bz = blockIdx.z;
  if constexpr (REMAP) {
    int id = blockIdx.x + 64 * (blockIdx.y + 4 * blockIdx.z);
    bx = ((id & 7) << 3) + ((id >> 3) & 7);
    by = (id >> 6) & 3;
    bz = id >> 8;
  }

  const bf16* Aa = bz ? Aa1 : Aa0;
  const bf16* Ac = bz ? Ac1 : Ac0;
  bf16*  ob = bz ? ob1 : ob0;
  float* of = bz ? of1 : of0;
  const float* res = bz ? res1 : res0;

  const int tid = threadIdx.x;
  const int lane = tid & 63;
  const int w = tid >> 6;
  const int wr = w >> 1, wc = w & 1;
  const int m0r = bx * 128;
  const int n0 = by * BN;
  const int r15 = lane & 15, g = lane >> 4, rb = r15 & 7;
  const int l3 = lane >> 3, l7 = lane & 7;
  const int swzc = (l7 ^ l3) * 8;

  __shared__ bf16 At[2][8192];
  __shared__ bf16 Bt[2][BN * 64];

  const bf16* aA = Aa + (size_t)(m0r + w*32 + l3) * LDA + swzc;
  const bf16* aC = (MODE == 3) ? (Ac + (size_t)(m0r + w*32 + l3) * 256 + swzc) : nullptr;
  const bf16* bB = Wt + (size_t)(n0 + w*(BN/4) + l3) * KD + swzc;
  const int adst = (w*32) * 64;
  const int bdst = (w*(BN/4)) * 64;

  auto stage = [&](int buf, int kc) {
    const bf16* ab; int kcol;
    if constexpr (MODE == 3) {
      if (kc < 4) { ab = aA; kcol = kc * 64; } else { ab = aC; kcol = (kc - 4) * 64; }
    } else { ab = aA; kcol = kc * 64; }
#pragma unroll
    for (int i = 0; i < 4; i++)
      lds16(ab + kcol + (size_t)i * 8 * LDA, &At[buf][adst + i*512]);
#pragma unroll
    for (int i = 0; i < NF; i++)
      lds16(bB + kc*64 + (size_t)i * 8 * KD, &Bt[buf][bdst + i*512]);
  };

  f32x4 acc[4][NF];
#pragma unroll
  for (int i = 0; i < 4; i++)
#pragma unroll
    for (int j = 0; j < NF; j++) acc[i][j] = f32x4{0.f, 0.f, 0.f, 0.f};

  const int rx0 = ((0*4 + g) ^ rb) << 4;
  const int rx1 = ((1*4 + g) ^ rb) << 4;

  auto compute = [&](int cur) {
    const char* Ap = (const char*)&At[cur][0];
    const char* Bp = (const char*)&Bt[cur][0];
    __builtin_amdgcn_s_setprio(1);
#pragma unroll
    for (int ks = 0; ks < 2; ++ks) {
      const int rx = ks ? rx1 : rx0;
      bf16x8 af[4], bfr[NF];
#pragma unroll
      for (int mf = 0; mf < 4; ++mf)
        af[mf] = *reinterpret_cast<const bf16x8*>(Ap + (wr*64 + mf*16 + r15) * 128 + rx);
#pragma unroll
      for (int nf = 0; nf < NF; ++nf)
        bfr[nf] = *reinterpret_cast<const bf16x8*>(Bp + (wc*(BN/2) + nf*16 + r15) * 128 + rx);
#pragma unroll
      for (int mf = 0; mf < 4; ++mf)
#pragma unroll
        for (int nf = 0; nf < NF; ++nf)
          acc[mf][nf] = MFMA(af[mf], bfr[nf], acc[mf][nf]);
    }
    __builtin_amdgcn_s_setprio(0);
  };

  stage(0, 0);
  int cur = 0;
  for (int kc = 0; kc < NKC - 1; ++kc) {
    stage(cur ^ 1, kc + 1);
    if constexpr (NF == 4) asm volatile("s_waitcnt vmcnt(8)" ::: "memory");
    else                   asm volatile("s_waitcnt vmcnt(6)" ::: "memory");
    __builtin_amdgcn_sched_barrier(0);
    __builtin_amdgcn_s_barrier();
    __builtin_amdgcn_sched_barrier(0);
    compute(cur);
    asm volatile("s_waitcnt lgkmcnt(0)" ::: "memory");
    __builtin_amdgcn_sched_barrier(0);
    __builtin_amdgcn_s_barrier();
    __builtin_amdgcn_sched_barrier(0);
    cur ^= 1;
  }
  asm volatile("s_waitcnt vmcnt(0)" ::: "memory");
  __builtin_amdgcn_sched_barrier(0);
  __builtin_amdgcn_s_barrier();
  __builtin_amdgcn_sched_barrier(0);
  compute(cur);

  // ---- epilogue ----
#pragma unroll
  for (int mf = 0; mf < 4; ++mf)
#pragma unroll
    for (int nf = 0; nf < NF; ++nf) {
      f32x4 c = acc[mf][nf];
      int cg = n0 + wc*(BN/2) + nf*16 + r15;
#pragma unroll
      for (int r = 0; r < 4; ++r) {
        int rg = m0r + wr*64 + mf*16 + g*4 + r;
        if constexpr (MODE == 5) {
          int b = rg >> 11, n = rg & 2047;
          if (cg < 256) {
            float val = (c[r] + bias[cg]) * SS2;
            int h = cg >> 6, dh = cg & 63;
            ob[(((size_t)(b*Hh + h)) * Nn + n) * 64 + dh] = (bf16)val;
          } else {
            int c2 = cg - 256;
            float val = c[r] + res[c2];            // res carries bv
            int h = c2 >> 6, dh = c2 & 63;
            ((bf16*)of)[(((size_t)(b*Hh + h)) * 64 + dh) * Nn + n] = (bf16)val;
          }
        } else if constexpr (MODE == 6) {
          if (rg < 256) ob[(size_t)cg * 512 + 256 + rg] = (bf16)c[r];
          else if (rg == 256) of[cg] = c[r] + bias[cg];   // bias = bf1
        } else if constexpr (MODE == 3) {
          ob[(size_t)rg * 512 + cg] = (bf16)(c[r] + bias[cg]);
        } else {   // MODE 4
          of[(size_t)rg * 256 + cg] = c[r] + bias[cg] + (float)Ac[(size_t)rg * 256 + cg];
        }
      }
    }
}

// ---------------- fused dual-direction attention: j-SPLIT wave pairs ----------------
// Block = 512 threads = 8 waves = 4 i-groups x 2 j-halves. Each wave: 32 q-rows
// (proven best MFMA/VALU/LDS ratio), 16 of 32 j-tiles. Per-half double-buffered
// K/V (64 KB/block) -> 2 blocks/CU = 4 waves/SIMD (2x TLP vs round 7).
// compute_tile identical to round 7 (32x32 MFMA, in-register P via exp2 +
// cvt_pk + permlane32_swap, rowsum via mfma(P, ones)). Halves combine
// acc/rowsum via LDS in the epilogue (plain sums - no max bookkeeping).
__global__ __launch_bounds__(512, 4) void attn_k(
    const bf16* qks0, const bf16* qks1, const bf16* vT0, const bf16* vT1,
    bf16* m0o, bf16* m1o) {
  const int B = blockIdx.x + 16 * (blockIdx.y + 16 * blockIdx.z);
  const int xcd = B & 7, kk = B >> 3;          // kk 0..63
  const int group = 4 * xcd + (kk >> 4);       // 0..31 = dir*16 + bh
  const int it = kk & 15;
  const int bh = group & 15, dir = group >> 4;

  const bf16* Q  = (dir ? qks1 : qks0) + (size_t)bh * (Nn * 64);
  const bf16* Kp = (dir ? qks0 : qks1) + (size_t)bh * (Nn * 64);
  const bf16* Vp = (dir ? vT0  : vT1 ) + (size_t)bh * (64 * Nn);
  bf16* out = dir ? m1o : m0o;
  const int b = bh >> 2, h = bh & 3;

  const int tid = threadIdx.x, lane = tid & 63, w = tid >> 6;
  const int ig = w >> 1, hj = w & 1;           // i-group 0..3, j-half 0..1
  const int l31 = lane & 31, hi = lane >> 5, xr = l31 & 7;
  const int iw = it * 128 + ig * 32;           // wave's first q-row

  __shared__ char smem[65536];
  bf16* KV = (bf16*)smem;
  // K(hj,buf) at elem  hj*8192 + buf*4096 ; V(hj,buf) at 16384 + hj*8192 + buf*4096
  const int kbase = hj * 8192;
  const int vbase = 16384 + hj * 8192;

  // ---- Q fragments (B-operand: col i = l31, k d = kt*16 + hi*8 + e) ----
  bf16x8 qf[4];
#pragma unroll
  for (int kt = 0; kt < 4; ++kt)
    qf[kt] = *reinterpret_cast<const bf16x8*>(
        &Q[(size_t)(iw + l31) * 64 + kt*16 + hi*8]);

  bf16x8 ones;
#pragma unroll
  for (int i = 0; i < 8; ++i) ones[i] = (bf16)1.0f;

  f32x16 acc[2]; acc[0] = zero16(); acc[1] = zero16();
  f32x16 rsacc = zero16();

  // ---- staging (pre-swizzled global sources, linear LDS dests) ----
  const int l3 = lane >> 3, l7 = lane & 7;
  const int swz = ((l7 ^ l3) * 8);
  const bf16* ks0 = Kp + (size_t)(ig*16 +     l3) * 64 + swz;
  const bf16* ks1 = Kp + (size_t)(ig*16 + 8 + l3) * 64 + swz;
  const bf16* vs0 = Vp + (size_t)(ig*16 +     l3) * 2048 + swz;
  const bf16* vs1 = Vp + (size_t)(ig*16 + 8 + l3) * 2048 + swz;
  const int kd0 = (ig*16    ) * 64;
  const int kd1 = (ig*16 + 8) * 64;

  auto stage = [&](int buf, int j0) {
    lds16(ks0 + (size_t)j0 * 64, KV + kbase + buf*4096 + kd0);
    lds16(ks1 + (size_t)j0 * 64, KV + kbase + buf*4096 + kd1);
    lds16(vs0 + j0,              KV + vbase + buf*4096 + kd0);
    lds16(vs1 + j0,              KV + vbase + buf*4096 + kd1);
  };

  // read-offset tables (bytes)
  int kby[2][4], vby[2][4];
#pragma unroll
  for (int jm = 0; jm < 2; ++jm)
#pragma unroll
    for (int kt = 0; kt < 4; ++kt)
      kby[jm][kt] = (jm*32 + l31) * 128 + (((2*kt + hi) ^ xr) << 4);
#pragma unroll
  for (int nt = 0; nt < 2; ++nt)
#pragma unroll
    for (int gg = 0; gg < 4; ++gg)
      vby[nt][gg] = (nt*32 + l31) * 128 + (((2*gg + hi) ^ xr) << 4);

  auto compute_tile = [&](int cur) {
    const char* Kb = (const char*)(KV + kbase + cur*4096);
    const char* Vb = (const char*)(KV + vbase + cur*4096);
    // --- QK^T: S^T[j][i], col i = l31, rows j from reg layout ---
    f32x16 st[2];
    __builtin_amdgcn_s_setprio(1);
#pragma unroll
    for (int jm = 0; jm < 2; ++jm) {
      f32x16 t = zero16();
#pragma unroll
      for (int kt = 0; kt < 4; ++kt) {
        bf16x8 kf = *reinterpret_cast<const bf16x8*>(Kb + kby[jm][kt]);
        t = MFMA32(kf, qf[kt], t);
      }
      st[jm] = t;
    }
    __builtin_amdgcn_s_setprio(0);
    // --- exp2 + cvt_pk pack + permlane32_swap -> PA fragments (in-register) ---
    bf16x8 pa[4];
#pragma unroll
    for (int jm = 0; jm < 2; ++jm) {
      unsigned dw[8];
#pragma unroll
      for (int s = 0; s < 8; ++s) {
        float e0 = __builtin_amdgcn_exp2f(st[jm][2*s]);
        float e1 = __builtin_amdgcn_exp2f(st[jm][2*s + 1]);
        asm("v_cvt_pk_bf16_f32 %0, %1, %2" : "=v"(dw[s]) : "v"(e0), "v"(e1));
      }
#pragma unroll
      for (int kt2 = 0; kt2 < 2; ++kt2) {
        unsigned a0 = dw[4*kt2 + 0], b0 = dw[4*kt2 + 2];
        unsigned a1 = dw[4*kt2 + 1], b1 = dw[4*kt2 + 3];
        // a' = [a.lo | b.lo], b' = [a.hi | b.hi]
        asm volatile("v_permlane32_swap_b32 %0, %1" : "+v"(a0), "+v"(b0));
        asm volatile("v_permlane32_swap_b32 %0, %1" : "+v"(a1), "+v"(b1));
        u32x4 uu; uu[0] = a0; uu[1] = a1; uu[2] = b0; uu[3] = b1;
        pa[jm*2 + kt2] = __builtin_bit_cast(bf16x8, uu);
      }
    }
    // --- PV + rowsum (A = PA, rows i = l31; k = j 16 per tile) ---
    __builtin_amdgcn_s_setprio(1);
#pragma unroll
    for (int gg = 0; gg < 4; ++gg) {
      rsacc = MFMA32(pa[gg], ones, rsacc);
#pragma unroll
      for (int nt = 0; nt < 2; ++nt) {
        bf16x8 vf = *reinterpret_cast<const bf16x8*>(Vb + vby[nt][gg]);
        acc[nt] = MFMA32(pa[gg], vf, acc[nt]);
      }
    }
    __builtin_amdgcn_s_setprio(0);
  };

  // ---- pipelined main loop: 16 j-tiles per wave (half of 32), last peeled ----
  const int jt0 = hj << 4;
  stage(0, jt0 << 6);
  int cur = 0;
  for (int t = 0; t < 15; ++t) {
    stage(cur ^ 1, (jt0 + t + 1) << 6);
    asm volatile("s_waitcnt vmcnt(4)" ::: "memory");
    __builtin_amdgcn_sched_barrier(0);
    __builtin_amdgcn_s_barrier();
    __builtin_amdgcn_sched_barrier(0);
    compute_tile(cur);
    asm volatile("s_waitcnt lgkmcnt(0)" ::: "memory");
    __builtin_amdgcn_sched_barrier(0);
    __builtin_amdgcn_s_barrier();
    __builtin_amdgcn_sched_barrier(0);
    cur ^= 1;
  }
  asm volatile("s_waitcnt vmcnt(0)" ::: "memory");
  __builtin_amdgcn_sched_barrier(0);
  __builtin_amdgcn_s_barrier();
  __builtin_amdgcn_sched_barrier(0);
  compute_tile(cur);

  // ---- epilogue: combine halves via LDS (aliases K/V space), divide, write ----
  __syncthreads();                       // all K/V reads done; smem reusable
  float* Ex = (float*)smem;              // [ig][48][64] f32 = 48 KB
  if (hj == 1) {
#pragma unroll
    for (int nt = 0; nt < 2; ++nt)
#pragma unroll
      for (int r = 0; r < 16; ++r)
        Ex[(ig*48 + nt*16 + r) * 64 + lane] = acc[nt][r];
#pragma unroll
    for (int r = 0; r < 16; ++r)
      Ex[(ig*48 + 32 + r) * 64 + lane] = rsacc[r];
  }
  __syncthreads();
  if (hj == 0) {
#pragma unroll
    for (int r = 0; r < 16; ++r) {
      float rs = rsacc[r] + Ex[(ig*48 + 32 + r) * 64 + lane];
      float inv = 1.0f / rs;
      int row = iw + (r & 3) + 8*(r >> 2) + 4*hi;
#pragma unroll
      for (int nt = 0; nt < 2; ++nt) {
        float o = acc[nt][r] + Ex[(ig*48 + nt*16 + r) * 64 + lane];
        int col = h*64 + nt*32 + l31;
        out[((size_t)b * Nn + row) * 256 + col] = (bf16)(o * inv);
      }
    }
  }
}

// ---------------- LayerNorm + exact GELU: one wave per 512-col row ----------------
__global__ __launch_bounds__(256) void ln_gelu_k(
    bf16* hg, const float* g, const float* bb) {
  const int row = (blockIdx.x << 2) + (threadIdx.x >> 6);
  const int lane = threadIdx.x & 63;
  bf16* hr = hg + (size_t)row * 512 + lane * 8;
  bf16x8 v = *reinterpret_cast<const bf16x8*>(hr);
  float f[8];
  float s = 0.f, sq = 0.f;
#pragma unroll
  for (int i = 0; i < 8; ++i) { f[i] = (float)v[i]; s += f[i]; sq += f[i]*f[i]; }
#pragma unroll
  for (int m = 1; m < 64; m <<= 1) { s += __shfl_xor(s, m); sq += __shfl_xor(sq, m); }
  float mu = s * (1.f / 512.f);
  float var = sq * (1.f / 512.f) - mu * mu;
  float rsv = rsqrtf(var + 1e-5f);
  f32x4 g0 = *reinterpret_cast<const f32x4*>(&g[lane*8]);
  f32x4 g1 = *reinterpret_cast<const f32x4*>(&g[lane*8 + 4]);
  f32x4 b0 = *reinterpret_cast<const f32x4*>(&bb[lane*8]);
  f32x4 b1 = *reinterpret_cast<const f32x4*>(&bb[lane*8 + 4]);
  bf16x8 o;
#pragma unroll
  for (int i = 0; i < 8; ++i) {
    float gv = (i < 4) ? g0[i] : g1[i-4];
    float bv = (i < 4) ? b0[i] : b1[i-4];
    float xn = (f[i] - mu) * rsv * gv + bv;
    float ge = 0.5f * xn * (1.f + erff(xn * 0.70710678118f));
    o[i] = (bf16)ge;
  }
  *reinterpret_cast<bf16x8*>(hr) = o;
}

extern "C" void kernel_launch(void* const* d_in, const int* in_sizes, int n_in,
                              void* d_out, int out_size, void* d_ws, size_t ws_size,
                              hipStream_t stream) {
  (void)in_sizes; (void)n_in; (void)out_size; (void)ws_size;
  const float* x0   = (const float*)d_in[0];
  const float* x1   = (const float*)d_in[1];
  const float* Wqk  = (const float*)d_in[2];
  const float* bqk  = (const float*)d_in[3];
  const float* Wv   = (const float*)d_in[4];
  const float* bv   = (const float*)d_in[5];
  const float* Wout = (const float*)d_in[6];
  const float* bout = (const float*)d_in[7];
  const float* Wf1  = (const float*)d_in[8];
  const float* bf1  = (const float*)d_in[9];
  const float* ln_g = (const float*)d_in[10];
  const float* ln_b = (const float*)d_in[11];
  const float* Wf2  = (const float*)d_in[12];
  const float* bf2  = (const float*)d_in[13];
  float* y = (float*)d_out;

  bf16* p = (bf16*)d_ws;
  bf16* wqkv_t = p; p += 131072;
  bf16* wout_b = p; p += 98304;
  bf16* wfold_t = p; p += 262144;
  bf16* wf1b_t = p; p += 131072;
  bf16* wf2_t  = p; p += 131072;
  float* bfold = (float*)p; p += 1024;     // 512 f32
  bf16* xb0  = p; p += 2097152;
  bf16* xb1  = p; p += 2097152;
  bf16* qks0 = p; p += 2097152;
  bf16* qks1 = p; p += 2097152;
  bf16* vT0  = p; p += 2097152;
  bf16* vT1  = p; p += 2097152;
  bf16* m0   = p; p += 2097152;
  bf16* m1   = p; p += 2097152;
  bf16* hg0  = p; p += 4194304;
  bf16* hg1  = p; p += 4194304;

  dim3 blk(256);
  prep_k<<<6528, blk, 0, stream>>>(Wqk, Wv, Wout, bout, Wf1, Wf2, x0, x1,
                                   wqkv_t, wout_b, wfold_t, wf1b_t, wf2_t, xb0, xb1);
  // weight fold: Wc = [Wout; bout] @ Wf1b  -> wfold_t cols 256-511, bfold
  gemm_k<6,128,2,0><<<dim3(3, 4, 1), blk, 0, stream>>>(
      wout_b, wout_b, nullptr, nullptr, wf1b_t, bf1,
      wfold_t, wfold_t, bfold, bfold, nullptr, nullptr);
  gemm_k<5,128,2,1><<<dim3(64, 4, 2), blk, 0, stream>>>(
      xb0, xb1, nullptr, nullptr, wqkv_t, bqk,
      qks0, qks1, (float*)vT0, (float*)vT1, bv, bv);
  attn_k<<<dim3(16, 16, 2), dim3(512), 0, stream>>>(qks0, qks1, vT0, vT1, m0, m1);
  gemm_k<3,128,2,1><<<dim3(64, 4, 2), blk, 0, stream>>>(
      xb0, xb1, m0, m1, wfold_t, bfold,
      hg0, hg1, nullptr, nullptr, nullptr, nullptr);
  ln_gelu_k<<<dim3(4096), blk, 0, stream>>>(hg0, ln_g, ln_b);
  gemm_k<4,64,3,1><<<dim3(64, 4, 2), blk, 0, stream>>>(
      hg0, hg1, xb0, xb1, wf2_t, bf2,
      nullptr, nullptr, y, y + 2097152, nullptr, nullptr);
}